// Round 10
// baseline (184.447 us; speedup 1.0000x reference)
//
#include <hip/hip_runtime.h>
#include <hip/hip_bf16.h>
#include <math.h>

#define BB 8
#define MM 4096
#define DD 512
#define SS 128

typedef _Float16 f16;
typedef _Float16 f16x4 __attribute__((ext_vector_type(4)));
typedef _Float16 f16x8 __attribute__((ext_vector_type(8)));
typedef float f32x4 __attribute__((ext_vector_type(4)));

struct f16pair { f16 h; f16 l; };
// 2-way f16 split: x ~= h + l, residual <= 2^-22 |x|
__device__ __forceinline__ f16pair split2(float x) {
  f16pair p;
  p.h = (f16)x;
  p.l = (f16)(x - (float)p.h);
  return p;
}

// split a float4 into two f16x4 and store to LDS
__device__ __forceinline__ void split_store4(float4 v, f16* p1, f16* p2) {
  f16x4 h, l;
  f16pair p;
  p = split2(v.x); h[0] = p.h; l[0] = p.l;
  p = split2(v.y); h[1] = p.h; l[1] = p.l;
  p = split2(v.z); h[2] = p.h; l[2] = p.l;
  p = split2(v.w); h[3] = p.h; l[3] = p.l;
  *(f16x4*)p1 = h;
  *(f16x4*)p2 = l;
}

// split two float4 registers into two f16x8 fragments
__device__ __forceinline__ void cvt8r(float4 v0, float4 v1, f16x8& h, f16x8& l) {
  f16pair q;
  q = split2(v0.x); h[0] = q.h; l[0] = q.l;
  q = split2(v0.y); h[1] = q.h; l[1] = q.l;
  q = split2(v0.z); h[2] = q.h; l[2] = q.l;
  q = split2(v0.w); h[3] = q.h; l[3] = q.l;
  q = split2(v1.x); h[4] = q.h; l[4] = q.l;
  q = split2(v1.y); h[5] = q.h; l[5] = q.l;
  q = split2(v1.z); h[6] = q.h; l[6] = q.l;
  q = split2(v1.w); h[7] = q.h; l[7] = q.l;
}

// ---------------------------------------------------------------------------
// Kernel 1 (fused): blocks 0..7 = memory row write + usage decay;
// blocks 8..519 = qp = query @ W via f16 3-term MFMA (32R x 32N x 32K,
// one 16x16 tile per wave, 512 blocks = 2/CU). A register-prefetched from
// global; W transposed+split into double-buffered LDS.
// ---------------------------------------------------------------------------
#define QLSTR 40  // LDS row stride in f16 elems

__global__ __launch_bounds__(256) void prep_kernel(
    float* __restrict__ memory, const float* __restrict__ usage,
    const float* __restrict__ content, const float* __restrict__ wstr,
    const float* __restrict__ ttab, const float* __restrict__ decay_p,
    const int* __restrict__ widx, float* __restrict__ usage_out,
    const float* __restrict__ query, const float* __restrict__ W,
    f16* __restrict__ q1, f16* __restrict__ q2) {
  __shared__ __align__(16) f16 B1s[2][32 * QLSTR];
  __shared__ __align__(16) f16 B2s[2][32 * QLSTR];
  const int tid = threadIdx.x;

  if (blockIdx.x < 8) {  // ---- update part ----
    const int b = blockIdx.x;
    int idx = widx[b] % MM; if (idx < 0) idx += MM;
    const float ws = wstr[b];
    const float decay = decay_p[0];
    for (int d = tid; d < DD; d += blockDim.x) {
      float cw = content[b * DD + d] + ttab[(size_t)idx * DD + d];
      size_t off = (size_t)b * MM * DD + (size_t)idx * DD + d;
      float old = memory[off];
      memory[off] = old * (1.0f - ws) + cw * ws;
    }
    for (int m = tid; m < MM; m += blockDim.x) {
      float u = usage[b * MM + m] * decay;
      if (m == idx) u += ws;
      usage_out[b * MM + m] = u;
    }
    return;
  }

  // ---- qp part: 32R x 32N, one 16x16 tile per wave ----
  const int bid = blockIdx.x - 8;
  const int n0 = (bid & 15) * 32;
  const int r0 = (bid >> 4) * 32;
  const int wv = tid >> 6, lane = tid & 63;
  const int quad = lane >> 4, rr = lane & 15;
  const int wr = wv & 1, wc = wv >> 1;

  // B staging: 32 k-rows x 8 float4-cols = 256 chunks, 1/thread
  const int krow = tid >> 3, nc = tid & 7;

  f32x4 acc;
#pragma unroll
  for (int c = 0; c < 4; ++c) acc[c] = 0.f;

  const int arow = r0 + wr * 16 + rr;
  float4 wv4 = *(const float4*)(W + (size_t)krow * DD + n0 + nc * 4);
  float4 aq0 = *(const float4*)(query + (size_t)arow * DD + quad * 8);
  float4 aq1 = *(const float4*)(query + (size_t)arow * DD + quad * 8 + 4);
  float4 an0, an1;
  {  // write W buf 0 (transposed)
    float e[4] = {wv4.x, wv4.y, wv4.z, wv4.w};
#pragma unroll
    for (int i = 0; i < 4; ++i) {
      f16pair p = split2(e[i]);
      B1s[0][(nc * 4 + i) * QLSTR + krow] = p.h;
      B2s[0][(nc * 4 + i) * QLSTR + krow] = p.l;
    }
  }
  __syncthreads();

  for (int ks = 0; ks < 16; ++ks) {
    const int cur = ks & 1;
    if (ks < 15) {  // prefetch k+1 (W + A)
      int k0 = (ks + 1) * 32;
      wv4 = *(const float4*)(W + (size_t)(k0 + krow) * DD + n0 + nc * 4);
      an0 = *(const float4*)(query + (size_t)arow * DD + k0 + quad * 8);
      an1 = *(const float4*)(query + (size_t)arow * DD + k0 + quad * 8 + 4);
    }
    f16x8 a1, a2;
    cvt8r(aq0, aq1, a1, a2);
    int col = wc * 16 + rr;
    f16x8 b1 = *(const f16x8*)&B1s[cur][col * QLSTR + quad * 8];
    f16x8 b2 = *(const f16x8*)&B2s[cur][col * QLSTR + quad * 8];
    acc = __builtin_amdgcn_mfma_f32_16x16x32_f16(a1, b2, acc, 0, 0, 0);
    acc = __builtin_amdgcn_mfma_f32_16x16x32_f16(a2, b1, acc, 0, 0, 0);
    acc = __builtin_amdgcn_mfma_f32_16x16x32_f16(a1, b1, acc, 0, 0, 0);
    if (ks < 15) {
      float e[4] = {wv4.x, wv4.y, wv4.z, wv4.w};
#pragma unroll
      for (int i = 0; i < 4; ++i) {
        f16pair p = split2(e[i]);
        B1s[cur ^ 1][(nc * 4 + i) * QLSTR + krow] = p.h;
        B2s[cur ^ 1][(nc * 4 + i) * QLSTR + krow] = p.l;
      }
      aq0 = an0; aq1 = an1;
    }
    __syncthreads();
  }
  // epilogue: C/D layout col=lane&15, row=quad*4+reg
#pragma unroll
  for (int reg = 0; reg < 4; ++reg) {
    int row = r0 + wr * 16 + quad * 4 + reg;
    int col = n0 + wc * 16 + rr;
    f16pair p = split2(acc[reg]);
    q1[(size_t)row * DD + col] = p.h;
    q2[(size_t)row * DD + col] = p.l;
  }
}

// ---------------------------------------------------------------------------
// Kernel 2: scores via f16 2-way-split MFMA, 3 terms.
// Tile 128(S) x 32(M) x 32(K), grid 1024 (4 blocks/CU = 16 waves/CU for
// latency hiding; total HBM traffic unchanged — each block owns disjoint
// M-rows). XCD-pinned batch, double-buffered LDS for memory (fp32 ->
// split2 fused), q direct from global (L2).
// ---------------------------------------------------------------------------
#define LSTR 40  // LDS row stride in f16 elems

__global__ __launch_bounds__(256, 2) void gemm_scores_mfma(
    const f16* __restrict__ q1_g, const f16* __restrict__ q2_g,
    const float* __restrict__ mem, float* __restrict__ sc_out) {
  __shared__ __align__(16) f16 m1_s[2][32 * LSTR];
  __shared__ __align__(16) f16 m2_s[2][32 * LSTR];
  const int tid = threadIdx.x;
  const int b = blockIdx.x & 7;                 // XCD-pinned batch
  const int j0 = (blockIdx.x >> 3) * 32;
  const int wv = tid >> 6, lane = tid & 63;
  const int quad = lane >> 4, rr = lane & 15;

  const f16* q1b = q1_g + (size_t)b * SS * DD;
  const f16* q2b = q2_g + (size_t)b * SS * DD;
  // m staging: 32 rows x 8 float4 = 256 chunks, 1/thread
  const int mrow = tid >> 3, mk = tid & 7;
  const float* mbase = mem + ((size_t)b * MM + j0) * DD;

  f32x4 acc[2][2];
#pragma unroll
  for (int i = 0; i < 2; ++i)
#pragma unroll
    for (int j = 0; j < 2; ++j)
#pragma unroll
      for (int c = 0; c < 4; ++c) acc[i][j][c] = 0.f;

  float4 mr0;
  f16x8 a1c[2], a2c[2], a1n[2], a2n[2];

  mr0 = *(const float4*)(mbase + (size_t)mrow * DD + mk * 4);
#pragma unroll
  for (int st = 0; st < 2; ++st) {
    int srow = wv * 32 + st * 16 + rr;
    a1c[st] = *(const f16x8*)(q1b + (size_t)srow * DD + quad * 8);
    a2c[st] = *(const f16x8*)(q2b + (size_t)srow * DD + quad * 8);
  }
  split_store4(mr0, &m1_s[0][mrow * LSTR + mk * 4], &m2_s[0][mrow * LSTR + mk * 4]);
  __syncthreads();

  for (int ks = 0; ks < 16; ++ks) {
    const int cur = ks & 1;
    if (ks < 15) {  // prefetch k+1; lands during the MFMA phase
      int k0 = (ks + 1) * 32;
      mr0 = *(const float4*)(mbase + (size_t)mrow * DD + k0 + mk * 4);
#pragma unroll
      for (int st = 0; st < 2; ++st) {
        int srow = wv * 32 + st * 16 + rr;
        a1n[st] = *(const f16x8*)(q1b + (size_t)srow * DD + k0 + quad * 8);
        a2n[st] = *(const f16x8*)(q2b + (size_t)srow * DD + k0 + quad * 8);
      }
    }
#pragma unroll
    for (int jt = 0; jt < 2; ++jt) {
      int brow = jt * 16 + rr;
      f16x8 b1 = *(const f16x8*)&m1_s[cur][brow * LSTR + quad * 8];
      f16x8 b2 = *(const f16x8*)&m2_s[cur][brow * LSTR + quad * 8];
#pragma unroll
      for (int st = 0; st < 2; ++st) {
        acc[st][jt] = __builtin_amdgcn_mfma_f32_16x16x32_f16(a1c[st], b2, acc[st][jt], 0, 0, 0);
        acc[st][jt] = __builtin_amdgcn_mfma_f32_16x16x32_f16(a2c[st], b1, acc[st][jt], 0, 0, 0);
        acc[st][jt] = __builtin_amdgcn_mfma_f32_16x16x32_f16(a1c[st], b1, acc[st][jt], 0, 0, 0);
      }
    }
    if (ks < 15) {  // write k+1 into the other buffer (no barrier before)
      const int nxt = cur ^ 1;
      split_store4(mr0, &m1_s[nxt][mrow * LSTR + mk * 4], &m2_s[nxt][mrow * LSTR + mk * 4]);
#pragma unroll
      for (int st = 0; st < 2; ++st) { a1c[st] = a1n[st]; a2c[st] = a2n[st]; }
    }
    __syncthreads();
  }
  const float scl = 0.04419417382415922f;  // 1/sqrt(512)
  float* C = sc_out + (size_t)b * SS * MM;
#pragma unroll
  for (int st = 0; st < 2; ++st)
#pragma unroll
    for (int jt = 0; jt < 2; ++jt)
#pragma unroll
      for (int reg = 0; reg < 4; ++reg) {
        int srow = wv * 32 + st * 16 + quad * 4 + reg;
        int scol = j0 + jt * 16 + rr;
        C[(size_t)srow * MM + scol] = acc[st][jt][reg] * scl;
      }
}

// ---------------------------------------------------------------------------
// Kernel 3: per (b,s) row select — REGISTER-RESIDENT. Each thread owns 16
// values (4 float4 chunks) in VGPRs; radix passes are pure VALU (no LDS
// rescans). Survivor probs go to a 128-entry LDS list for the gather.
// XCD-pinned (b = blockIdx&7).
// ---------------------------------------------------------------------------
__device__ __forceinline__ unsigned fkey(float f) {
  unsigned u = __float_as_uint(f);
  return (u & 0x80000000u) ? ~u : (u | 0x80000000u);
}
__device__ __forceinline__ float finv(unsigned u) {
  unsigned b = (u & 0x80000000u) ? (u & 0x7fffffffu) : ~u;
  return __uint_as_float(b);
}

#define NKEPT 128  // top-k=64 + tie margin (ties need bit-equal fp32)

__global__ __launch_bounds__(256) void select_kernel(
    const float* __restrict__ scores, const int* __restrict__ vmask,
    const int* __restrict__ widx, const int* __restrict__ topk,
    const float* __restrict__ memory, float* __restrict__ retrieved,
    float* __restrict__ attn) {
  __shared__ unsigned histw[4 * 256];  // per-wave hist (pass 0); hist0 reused later
  __shared__ int kept_m[NKEPT];
  __shared__ float kept_p[NKEPT];
  __shared__ float red4[4];
  __shared__ unsigned sh_pref;
  __shared__ int sh_k, sh_nkept;
  __shared__ float sh_zinv;

  const int tid = threadIdx.x;
  const int b = blockIdx.x & 7, s = blockIdx.x >> 3;  // XCD-pinned batch
  const int lane = tid & 63, wv = tid >> 6;
  int wi = widx[b] % MM; if (wi < 0) wi += MM;
  const float4* srow4 = (const float4*)(scores + ((size_t)b * SS + s) * MM);
  const int4* vrow4 = (const int4*)(vmask + (size_t)b * MM);
  unsigned* hw = histw + wv * 256;

  if (tid == 0) { sh_pref = 0u; sh_nkept = 0; sh_k = topk[0]; }
  for (int i = tid; i < 1024; i += 256) histw[i] = 0u;
  __syncthreads();

  // load + mask into registers; fkeys; pass-0 histogram; row max
  float4 v[4];
  uint4 u[4];
  float lmax = -INFINITY;
#pragma unroll
  for (int j = 0; j < 4; ++j) {
    int m4 = tid + 256 * j;
    float4 x = srow4[m4];
    int4 mk = vrow4[m4];
    int mb = m4 * 4;
    if (!(mk.x || mb + 0 == wi)) x.x = -INFINITY;
    if (!(mk.y || mb + 1 == wi)) x.y = -INFINITY;
    if (!(mk.z || mb + 2 == wi)) x.z = -INFINITY;
    if (!(mk.w || mb + 3 == wi)) x.w = -INFINITY;
    v[j] = x;
    u[j].x = fkey(x.x); u[j].y = fkey(x.y);
    u[j].z = fkey(x.z); u[j].w = fkey(x.w);
    lmax = fmaxf(lmax, fmaxf(fmaxf(x.x, x.y), fmaxf(x.z, x.w)));
    atomicAdd(&hw[u[j].x >> 24], 1u);
    atomicAdd(&hw[u[j].y >> 24], 1u);
    atomicAdd(&hw[u[j].z >> 24], 1u);
    atomicAdd(&hw[u[j].w >> 24], 1u);
  }
#pragma unroll
  for (int off = 32; off > 0; off >>= 1)
    lmax = fmaxf(lmax, __shfl_xor(lmax, off));
  if (lane == 0) red4[wv] = lmax;
  __syncthreads();
  const float maxv = fmaxf(fmaxf(red4[0], red4[1]), fmaxf(red4[2], red4[3]));

  // radix select (4 passes). Pass 0 uses the 4-way per-wave hist already
  // built; passes 1-3 use a single 256-bin hist (matches are rare).
  for (int pass = 0; pass < 4; ++pass) {
    const int shift = 24 - pass * 8;
    if (pass > 0) {
      const unsigned pref = sh_pref;
      const unsigned hmask = 0xFFFFFFFFu << (shift + 8);
      histw[tid] = 0u;
      __syncthreads();
#pragma unroll
      for (int j = 0; j < 4; ++j) {
        if ((u[j].x & hmask) == pref) atomicAdd(&histw[(u[j].x >> shift) & 0xFFu], 1u);
        if ((u[j].y & hmask) == pref) atomicAdd(&histw[(u[j].y >> shift) & 0xFFu], 1u);
        if ((u[j].z & hmask) == pref) atomicAdd(&histw[(u[j].z >> shift) & 0xFFu], 1u);
        if ((u[j].w & hmask) == pref) atomicAdd(&histw[(u[j].w >> shift) & 0xFFu], 1u);
      }
      __syncthreads();
    }
    if (tid < 64) {
      const int l = tid;
      unsigned h0, h1, h2, h3;
      if (pass == 0) {
        h0 = histw[l * 4 + 0] + histw[256 + l * 4 + 0] + histw[512 + l * 4 + 0] + histw[768 + l * 4 + 0];
        h1 = histw[l * 4 + 1] + histw[256 + l * 4 + 1] + histw[512 + l * 4 + 1] + histw[768 + l * 4 + 1];
        h2 = histw[l * 4 + 2] + histw[256 + l * 4 + 2] + histw[512 + l * 4 + 2] + histw[768 + l * 4 + 2];
        h3 = histw[l * 4 + 3] + histw[256 + l * 4 + 3] + histw[512 + l * 4 + 3] + histw[768 + l * 4 + 3];
      } else {
        h0 = histw[l * 4 + 0]; h1 = histw[l * 4 + 1];
        h2 = histw[l * 4 + 2]; h3 = histw[l * 4 + 3];
      }
      unsigned lsum = h0 + h1 + h2 + h3;
      unsigned g = lsum;  // inclusive suffix scan across lanes
#pragma unroll
      for (int off = 1; off < 64; off <<= 1) {
        unsigned t = __shfl_down(g, off, 64);
        if (l + off < 64) g += t;
      }
      unsigned above = g - lsum;
      unsigned suf3 = h3 + above;
      unsigned suf2 = h2 + suf3;
      unsigned suf1 = h1 + suf2;
      unsigned suf0 = h0 + suf1;
      const unsigned kk = (unsigned)sh_k;
      const unsigned prefc = sh_pref;
      unsigned ge, geN;
      ge = suf0; geN = suf1;
      if (ge >= kk && geN < kk) { sh_pref = prefc | ((unsigned)(4 * l + 0) << shift); sh_k = (int)(kk - geN); }
      ge = suf1; geN = suf2;
      if (ge >= kk && geN < kk) { sh_pref = prefc | ((unsigned)(4 * l + 1) << shift); sh_k = (int)(kk - geN); }
      ge = suf2; geN = suf3;
      if (ge >= kk && geN < kk) { sh_pref = prefc | ((unsigned)(4 * l + 2) << shift); sh_k = (int)(kk - geN); }
      ge = suf3; geN = above;
      if (ge >= kk && geN < kk) { sh_pref = prefc | ((unsigned)(4 * l + 3) << shift); sh_k = (int)(kk - geN); }
    }
    __syncthreads();
  }
  const float thr = finv(sh_pref);

  // probs in registers + Z (wave-shuffle reduction)
  float4 pr[4];
  float lz = 0.f;
#pragma unroll
  for (int j = 0; j < 4; ++j) {
    float4 x = v[j];
    pr[j].x = (x.x >= thr) ? __expf(x.x - maxv) : 0.f;
    pr[j].y = (x.y >= thr) ? __expf(x.y - maxv) : 0.f;
    pr[j].z = (x.z >= thr) ? __expf(x.z - maxv) : 0.f;
    pr[j].w = (x.w >= thr) ? __expf(x.w - maxv) : 0.f;
    lz += pr[j].x + pr[j].y + pr[j].z + pr[j].w;
  }
#pragma unroll
  for (int off = 32; off > 0; off >>= 1) lz += __shfl_xor(lz, off);
  if (lane == 0) red4[wv] = lz;
  __syncthreads();
  if (tid == 0) sh_zinv = 1.0f / (red4[0] + red4[1] + red4[2] + red4[3]);
  __syncthreads();
  const float zinv = sh_zinv;

  // dense attn write (from registers) + kept list (index + raw prob)
  float4* arow4 = (float4*)(attn + ((size_t)b * SS + s) * MM);
#pragma unroll
  for (int j = 0; j < 4; ++j) {
    int m4 = tid + 256 * j;
    float4 p = pr[j];
    arow4[m4] = make_float4(p.x * zinv, p.y * zinv, p.z * zinv, p.w * zinv);
    int mb = m4 * 4;
    if (p.x > 0.f) { int q = atomicAdd(&sh_nkept, 1); if (q < NKEPT) { kept_m[q] = mb + 0; kept_p[q] = p.x; } }
    if (p.y > 0.f) { int q = atomicAdd(&sh_nkept, 1); if (q < NKEPT) { kept_m[q] = mb + 1; kept_p[q] = p.y; } }
    if (p.z > 0.f) { int q = atomicAdd(&sh_nkept, 1); if (q < NKEPT) { kept_m[q] = mb + 2; kept_p[q] = p.z; } }
    if (p.w > 0.f) { int q = atomicAdd(&sh_nkept, 1); if (q < NKEPT) { kept_m[q] = mb + 3; kept_p[q] = p.w; } }
  }
  __syncthreads();
  const int nk = min(sh_nkept, NKEPT);

  // retrieved[b][s][:] = sum_kept p * memory_row (float2 lanes, unrolled x4)
  float ax = 0.f, ay = 0.f;
  const float* mb_ = memory + (size_t)b * MM * DD;
  int i = 0;
  for (; i + 4 <= nk; i += 4) {
    int m0 = kept_m[i], m1 = kept_m[i + 1], m2 = kept_m[i + 2], m3 = kept_m[i + 3];
    float p0 = kept_p[i], p1 = kept_p[i + 1], p2 = kept_p[i + 2], p3 = kept_p[i + 3];
    float2 v0 = ((const float2*)(mb_ + (size_t)m0 * DD))[tid];
    float2 v1 = ((const float2*)(mb_ + (size_t)m1 * DD))[tid];
    float2 v2 = ((const float2*)(mb_ + (size_t)m2 * DD))[tid];
    float2 v3 = ((const float2*)(mb_ + (size_t)m3 * DD))[tid];
    ax += p0 * v0.x + p1 * v1.x + p2 * v2.x + p3 * v3.x;
    ay += p0 * v0.y + p1 * v1.y + p2 * v2.y + p3 * v3.y;
  }
  for (; i < nk; ++i) {
    int m = kept_m[i];
    float p = kept_p[i];
    float2 vv = ((const float2*)(mb_ + (size_t)m * DD))[tid];
    ax += p * vv.x;
    ay += p * vv.y;
  }
  float2* rrow = (float2*)(retrieved + ((size_t)b * SS + s) * DD);
  rrow[tid] = make_float2(ax * zinv, ay * zinv);
}

// ---------------------------------------------------------------------------
extern "C" void kernel_launch(void* const* d_in, const int* in_sizes, int n_in,
                              void* d_out, int out_size, void* d_ws,
                              size_t ws_size, hipStream_t stream) {
  float* memory = (float*)d_in[0];
  const float* usage = (const float*)d_in[1];
  const float* content = (const float*)d_in[2];
  const float* wstr = (const float*)d_in[3];
  const float* query = (const float*)d_in[4];
  const float* W = (const float*)d_in[5];
  const float* ttab = (const float*)d_in[6];
  const float* decay = (const float*)d_in[7];
  const int* vmask = (const int*)d_in[8];
  const int* widx = (const int*)d_in[9];
  const int* topk = (const int*)d_in[10];

  float* out = (float*)d_out;
  float* retrieved = out;                              // B*S*D floats
  float* attn = out + (size_t)BB * SS * DD;            // B*S*M floats
  float* usage_out = attn + (size_t)BB * SS * MM;      // B*M floats

  const size_t qsz = (size_t)BB * SS * DD;             // elems per q array
  float* scores = (float*)d_ws;                        // 16 MB
  f16* q1;
  f16* q2;
  size_t need = (size_t)BB * SS * MM * 4 + 2 * qsz * 2;
  if (ws_size >= need) {
    q1 = (f16*)(scores + (size_t)BB * SS * MM);
    q2 = q1 + qsz;
  } else {
    q2 = (f16*)(attn + (size_t)BB * SS * MM) - qsz;
    q1 = q2 - qsz;
  }

  prep_kernel<<<8 + 512, 256, 0, stream>>>(memory, usage, content, wstr, ttab,
                                           decay, widx, usage_out, query, W,
                                           q1, q2);
  gemm_scores_mfma<<<dim3((MM / 32) * BB), 256, 0, stream>>>(q1, q2, memory,
                                                             scores);
  select_kernel<<<dim3(SS * BB), 256, 0, stream>>>(scores, vmask, widx, topk,
                                                   memory, retrieved, attn);
}

// Round 11
// 172.869 us; speedup vs baseline: 1.0670x; 1.0670x over previous
//
#include <hip/hip_runtime.h>
#include <hip/hip_bf16.h>
#include <math.h>

#define BB 8
#define MM 4096
#define DD 512
#define SS 128

typedef _Float16 f16;
typedef _Float16 f16x4 __attribute__((ext_vector_type(4)));
typedef _Float16 f16x8 __attribute__((ext_vector_type(8)));
typedef float f32x4 __attribute__((ext_vector_type(4)));

struct f16pair { f16 h; f16 l; };
// 2-way f16 split: x ~= h + l, residual <= 2^-22 |x|
__device__ __forceinline__ f16pair split2(float x) {
  f16pair p;
  p.h = (f16)x;
  p.l = (f16)(x - (float)p.h);
  return p;
}

// split a float4 into two f16x4 and store to LDS
__device__ __forceinline__ void split_store4(float4 v, f16* p1, f16* p2) {
  f16x4 h, l;
  f16pair p;
  p = split2(v.x); h[0] = p.h; l[0] = p.l;
  p = split2(v.y); h[1] = p.h; l[1] = p.l;
  p = split2(v.z); h[2] = p.h; l[2] = p.l;
  p = split2(v.w); h[3] = p.h; l[3] = p.l;
  *(f16x4*)p1 = h;
  *(f16x4*)p2 = l;
}

// split two float4 registers into two f16x8 fragments
__device__ __forceinline__ void cvt8r(float4 v0, float4 v1, f16x8& h, f16x8& l) {
  f16pair q;
  q = split2(v0.x); h[0] = q.h; l[0] = q.l;
  q = split2(v0.y); h[1] = q.h; l[1] = q.l;
  q = split2(v0.z); h[2] = q.h; l[2] = q.l;
  q = split2(v0.w); h[3] = q.h; l[3] = q.l;
  q = split2(v1.x); h[4] = q.h; l[4] = q.l;
  q = split2(v1.y); h[5] = q.h; l[5] = q.l;
  q = split2(v1.z); h[6] = q.h; l[6] = q.l;
  q = split2(v1.w); h[7] = q.h; l[7] = q.l;
}

// ---------------------------------------------------------------------------
// Kernel 1 (fused): blocks 0..7 = memory row write + usage decay;
// blocks 8..519 = qp = query @ W via f16 3-term MFMA (32R x 32N x 32K,
// one 16x16 tile per wave, 512 blocks = 2/CU). A register-prefetched from
// global; W transposed+split into double-buffered LDS.
// ---------------------------------------------------------------------------
#define QLSTR 40  // LDS row stride in f16 elems

__global__ __launch_bounds__(256) void prep_kernel(
    float* __restrict__ memory, const float* __restrict__ usage,
    const float* __restrict__ content, const float* __restrict__ wstr,
    const float* __restrict__ ttab, const float* __restrict__ decay_p,
    const int* __restrict__ widx, float* __restrict__ usage_out,
    const float* __restrict__ query, const float* __restrict__ W,
    f16* __restrict__ q1, f16* __restrict__ q2) {
  __shared__ __align__(16) f16 B1s[2][32 * QLSTR];
  __shared__ __align__(16) f16 B2s[2][32 * QLSTR];
  const int tid = threadIdx.x;

  if (blockIdx.x < 8) {  // ---- update part ----
    const int b = blockIdx.x;
    int idx = widx[b] % MM; if (idx < 0) idx += MM;
    const float ws = wstr[b];
    const float decay = decay_p[0];
    for (int d = tid; d < DD; d += blockDim.x) {
      float cw = content[b * DD + d] + ttab[(size_t)idx * DD + d];
      size_t off = (size_t)b * MM * DD + (size_t)idx * DD + d;
      float old = memory[off];
      memory[off] = old * (1.0f - ws) + cw * ws;
    }
    for (int m = tid; m < MM; m += blockDim.x) {
      float u = usage[b * MM + m] * decay;
      if (m == idx) u += ws;
      usage_out[b * MM + m] = u;
    }
    return;
  }

  // ---- qp part: 32R x 32N, one 16x16 tile per wave ----
  const int bid = blockIdx.x - 8;
  const int n0 = (bid & 15) * 32;
  const int r0 = (bid >> 4) * 32;
  const int wv = tid >> 6, lane = tid & 63;
  const int quad = lane >> 4, rr = lane & 15;
  const int wr = wv & 1, wc = wv >> 1;

  // B staging: 32 k-rows x 8 float4-cols = 256 chunks, 1/thread
  const int krow = tid >> 3, nc = tid & 7;

  f32x4 acc;
#pragma unroll
  for (int c = 0; c < 4; ++c) acc[c] = 0.f;

  const int arow = r0 + wr * 16 + rr;
  float4 wv4 = *(const float4*)(W + (size_t)krow * DD + n0 + nc * 4);
  float4 aq0 = *(const float4*)(query + (size_t)arow * DD + quad * 8);
  float4 aq1 = *(const float4*)(query + (size_t)arow * DD + quad * 8 + 4);
  float4 an0, an1;
  {  // write W buf 0 (transposed)
    float e[4] = {wv4.x, wv4.y, wv4.z, wv4.w};
#pragma unroll
    for (int i = 0; i < 4; ++i) {
      f16pair p = split2(e[i]);
      B1s[0][(nc * 4 + i) * QLSTR + krow] = p.h;
      B2s[0][(nc * 4 + i) * QLSTR + krow] = p.l;
    }
  }
  __syncthreads();

  for (int ks = 0; ks < 16; ++ks) {
    const int cur = ks & 1;
    if (ks < 15) {  // prefetch k+1 (W + A)
      int k0 = (ks + 1) * 32;
      wv4 = *(const float4*)(W + (size_t)(k0 + krow) * DD + n0 + nc * 4);
      an0 = *(const float4*)(query + (size_t)arow * DD + k0 + quad * 8);
      an1 = *(const float4*)(query + (size_t)arow * DD + k0 + quad * 8 + 4);
    }
    f16x8 a1, a2;
    cvt8r(aq0, aq1, a1, a2);
    int col = wc * 16 + rr;
    f16x8 b1 = *(const f16x8*)&B1s[cur][col * QLSTR + quad * 8];
    f16x8 b2 = *(const f16x8*)&B2s[cur][col * QLSTR + quad * 8];
    acc = __builtin_amdgcn_mfma_f32_16x16x32_f16(a1, b2, acc, 0, 0, 0);
    acc = __builtin_amdgcn_mfma_f32_16x16x32_f16(a2, b1, acc, 0, 0, 0);
    acc = __builtin_amdgcn_mfma_f32_16x16x32_f16(a1, b1, acc, 0, 0, 0);
    if (ks < 15) {
      float e[4] = {wv4.x, wv4.y, wv4.z, wv4.w};
#pragma unroll
      for (int i = 0; i < 4; ++i) {
        f16pair p = split2(e[i]);
        B1s[cur ^ 1][(nc * 4 + i) * QLSTR + krow] = p.h;
        B2s[cur ^ 1][(nc * 4 + i) * QLSTR + krow] = p.l;
      }
      aq0 = an0; aq1 = an1;
    }
    __syncthreads();
  }
  // epilogue: C/D layout col=lane&15, row=quad*4+reg
#pragma unroll
  for (int reg = 0; reg < 4; ++reg) {
    int row = r0 + wr * 16 + quad * 4 + reg;
    int col = n0 + wc * 16 + rr;
    f16pair p = split2(acc[reg]);
    q1[(size_t)row * DD + col] = p.h;
    q2[(size_t)row * DD + col] = p.l;
  }
}

// ---------------------------------------------------------------------------
// Kernel 2: scores via f16 2-way-split MFMA, 3 terms.
// Tile 128(S) x 64(M) x 32(K), grid 512 (2 blocks/CU) — MEASURED OPTIMUM:
// 128M tile (R4) starves block count; 32M tile (R10) starves per-wave
// arithmetic intensity (q-load-paced, MfmaUtil 9%). XCD-pinned batch,
// double-buffered LDS for memory (fp32 -> split2 fused), q direct from
// global (L2-resident).
// ---------------------------------------------------------------------------
#define LSTR 40  // LDS row stride in f16 elems

__global__ __launch_bounds__(256, 2) void gemm_scores_mfma(
    const f16* __restrict__ q1_g, const f16* __restrict__ q2_g,
    const float* __restrict__ mem, float* __restrict__ sc_out) {
  __shared__ __align__(16) f16 m1_s[2][64 * LSTR];
  __shared__ __align__(16) f16 m2_s[2][64 * LSTR];
  const int tid = threadIdx.x;
  const int b = blockIdx.x & 7;                 // XCD-pinned batch
  const int j0 = (blockIdx.x >> 3) * 64;
  const int wv = tid >> 6, lane = tid & 63;
  const int quad = lane >> 4, rr = lane & 15;

  const f16* q1b = q1_g + (size_t)b * SS * DD;
  const f16* q2b = q2_g + (size_t)b * SS * DD;
  const int mrow = tid >> 3, mk = tid & 7;
  const float* mbase = mem + ((size_t)b * MM + j0) * DD;

  f32x4 acc[2][4];
#pragma unroll
  for (int i = 0; i < 2; ++i)
#pragma unroll
    for (int j = 0; j < 4; ++j)
#pragma unroll
      for (int c = 0; c < 4; ++c) acc[i][j][c] = 0.f;

  float4 mr0, mr1;
  f16x8 a1c[2], a2c[2], a1n[2], a2n[2];

  mr0 = *(const float4*)(mbase + (size_t)mrow * DD + mk * 4);
  mr1 = *(const float4*)(mbase + (size_t)(mrow + 32) * DD + mk * 4);
#pragma unroll
  for (int st = 0; st < 2; ++st) {
    int srow = wv * 32 + st * 16 + rr;
    a1c[st] = *(const f16x8*)(q1b + (size_t)srow * DD + quad * 8);
    a2c[st] = *(const f16x8*)(q2b + (size_t)srow * DD + quad * 8);
  }
  split_store4(mr0, &m1_s[0][mrow * LSTR + mk * 4], &m2_s[0][mrow * LSTR + mk * 4]);
  split_store4(mr1, &m1_s[0][(mrow + 32) * LSTR + mk * 4], &m2_s[0][(mrow + 32) * LSTR + mk * 4]);
  __syncthreads();

  for (int ks = 0; ks < 16; ++ks) {
    const int cur = ks & 1;
    if (ks < 15) {  // prefetch k+1; lands during the MFMA phase
      int k0 = (ks + 1) * 32;
      mr0 = *(const float4*)(mbase + (size_t)mrow * DD + k0 + mk * 4);
      mr1 = *(const float4*)(mbase + (size_t)(mrow + 32) * DD + k0 + mk * 4);
#pragma unroll
      for (int st = 0; st < 2; ++st) {
        int srow = wv * 32 + st * 16 + rr;
        a1n[st] = *(const f16x8*)(q1b + (size_t)srow * DD + k0 + quad * 8);
        a2n[st] = *(const f16x8*)(q2b + (size_t)srow * DD + k0 + quad * 8);
      }
    }
#pragma unroll
    for (int jt = 0; jt < 4; ++jt) {
      int brow = jt * 16 + rr;
      f16x8 b1 = *(const f16x8*)&m1_s[cur][brow * LSTR + quad * 8];
      f16x8 b2 = *(const f16x8*)&m2_s[cur][brow * LSTR + quad * 8];
#pragma unroll
      for (int st = 0; st < 2; ++st) {
        acc[st][jt] = __builtin_amdgcn_mfma_f32_16x16x32_f16(a1c[st], b2, acc[st][jt], 0, 0, 0);
        acc[st][jt] = __builtin_amdgcn_mfma_f32_16x16x32_f16(a2c[st], b1, acc[st][jt], 0, 0, 0);
        acc[st][jt] = __builtin_amdgcn_mfma_f32_16x16x32_f16(a1c[st], b1, acc[st][jt], 0, 0, 0);
      }
    }
    if (ks < 15) {  // write k+1 into the other buffer (no barrier before)
      const int nxt = cur ^ 1;
      split_store4(mr0, &m1_s[nxt][mrow * LSTR + mk * 4], &m2_s[nxt][mrow * LSTR + mk * 4]);
      split_store4(mr1, &m1_s[nxt][(mrow + 32) * LSTR + mk * 4], &m2_s[nxt][(mrow + 32) * LSTR + mk * 4]);
#pragma unroll
      for (int st = 0; st < 2; ++st) { a1c[st] = a1n[st]; a2c[st] = a2n[st]; }
    }
    __syncthreads();
  }
  const float scl = 0.04419417382415922f;  // 1/sqrt(512)
  float* C = sc_out + (size_t)b * SS * MM;
#pragma unroll
  for (int st = 0; st < 2; ++st)
#pragma unroll
    for (int jt = 0; jt < 4; ++jt)
#pragma unroll
      for (int reg = 0; reg < 4; ++reg) {
        int srow = wv * 32 + st * 16 + quad * 4 + reg;
        int scol = j0 + jt * 16 + rr;
        C[(size_t)srow * MM + scol] = acc[st][jt][reg] * scl;
      }
}

// ---------------------------------------------------------------------------
// Kernel 3: per (b,s) row select — REGISTER-RESIDENT. Each thread owns 16
// values (4 float4 chunks) in VGPRs; radix passes are pure VALU (no LDS
// rescans). Survivor probs go to a 128-entry LDS list for the gather.
// XCD-pinned (b = blockIdx&7).
// ---------------------------------------------------------------------------
__device__ __forceinline__ unsigned fkey(float f) {
  unsigned u = __float_as_uint(f);
  return (u & 0x80000000u) ? ~u : (u | 0x80000000u);
}
__device__ __forceinline__ float finv(unsigned u) {
  unsigned b = (u & 0x80000000u) ? (u & 0x7fffffffu) : ~u;
  return __uint_as_float(b);
}

#define NKEPT 128  // top-k=64 + tie margin (ties need bit-equal fp32)

__global__ __launch_bounds__(256) void select_kernel(
    const float* __restrict__ scores, const int* __restrict__ vmask,
    const int* __restrict__ widx, const int* __restrict__ topk,
    const float* __restrict__ memory, float* __restrict__ retrieved,
    float* __restrict__ attn) {
  __shared__ unsigned histw[4 * 256];  // per-wave hist (pass 0); hist0 reused later
  __shared__ int kept_m[NKEPT];
  __shared__ float kept_p[NKEPT];
  __shared__ float red4[4];
  __shared__ unsigned sh_pref;
  __shared__ int sh_k, sh_nkept;
  __shared__ float sh_zinv;

  const int tid = threadIdx.x;
  const int b = blockIdx.x & 7, s = blockIdx.x >> 3;  // XCD-pinned batch
  const int lane = tid & 63, wv = tid >> 6;
  int wi = widx[b] % MM; if (wi < 0) wi += MM;
  const float4* srow4 = (const float4*)(scores + ((size_t)b * SS + s) * MM);
  const int4* vrow4 = (const int4*)(vmask + (size_t)b * MM);
  unsigned* hw = histw + wv * 256;

  if (tid == 0) { sh_pref = 0u; sh_nkept = 0; sh_k = topk[0]; }
  for (int i = tid; i < 1024; i += 256) histw[i] = 0u;
  __syncthreads();

  // load + mask into registers; fkeys; pass-0 histogram; row max
  float4 v[4];
  uint4 u[4];
  float lmax = -INFINITY;
#pragma unroll
  for (int j = 0; j < 4; ++j) {
    int m4 = tid + 256 * j;
    float4 x = srow4[m4];
    int4 mk = vrow4[m4];
    int mb = m4 * 4;
    if (!(mk.x || mb + 0 == wi)) x.x = -INFINITY;
    if (!(mk.y || mb + 1 == wi)) x.y = -INFINITY;
    if (!(mk.z || mb + 2 == wi)) x.z = -INFINITY;
    if (!(mk.w || mb + 3 == wi)) x.w = -INFINITY;
    v[j] = x;
    u[j].x = fkey(x.x); u[j].y = fkey(x.y);
    u[j].z = fkey(x.z); u[j].w = fkey(x.w);
    lmax = fmaxf(lmax, fmaxf(fmaxf(x.x, x.y), fmaxf(x.z, x.w)));
    atomicAdd(&hw[u[j].x >> 24], 1u);
    atomicAdd(&hw[u[j].y >> 24], 1u);
    atomicAdd(&hw[u[j].z >> 24], 1u);
    atomicAdd(&hw[u[j].w >> 24], 1u);
  }
#pragma unroll
  for (int off = 32; off > 0; off >>= 1)
    lmax = fmaxf(lmax, __shfl_xor(lmax, off));
  if (lane == 0) red4[wv] = lmax;
  __syncthreads();
  const float maxv = fmaxf(fmaxf(red4[0], red4[1]), fmaxf(red4[2], red4[3]));

  // radix select (4 passes). Pass 0 uses the 4-way per-wave hist already
  // built; passes 1-3 use a single 256-bin hist (matches are rare).
  for (int pass = 0; pass < 4; ++pass) {
    const int shift = 24 - pass * 8;
    if (pass > 0) {
      const unsigned pref = sh_pref;
      const unsigned hmask = 0xFFFFFFFFu << (shift + 8);
      histw[tid] = 0u;
      __syncthreads();
#pragma unroll
      for (int j = 0; j < 4; ++j) {
        if ((u[j].x & hmask) == pref) atomicAdd(&histw[(u[j].x >> shift) & 0xFFu], 1u);
        if ((u[j].y & hmask) == pref) atomicAdd(&histw[(u[j].y >> shift) & 0xFFu], 1u);
        if ((u[j].z & hmask) == pref) atomicAdd(&histw[(u[j].z >> shift) & 0xFFu], 1u);
        if ((u[j].w & hmask) == pref) atomicAdd(&histw[(u[j].w >> shift) & 0xFFu], 1u);
      }
      __syncthreads();
    }
    if (tid < 64) {
      const int l = tid;
      unsigned h0, h1, h2, h3;
      if (pass == 0) {
        h0 = histw[l * 4 + 0] + histw[256 + l * 4 + 0] + histw[512 + l * 4 + 0] + histw[768 + l * 4 + 0];
        h1 = histw[l * 4 + 1] + histw[256 + l * 4 + 1] + histw[512 + l * 4 + 1] + histw[768 + l * 4 + 1];
        h2 = histw[l * 4 + 2] + histw[256 + l * 4 + 2] + histw[512 + l * 4 + 2] + histw[768 + l * 4 + 2];
        h3 = histw[l * 4 + 3] + histw[256 + l * 4 + 3] + histw[512 + l * 4 + 3] + histw[768 + l * 4 + 3];
      } else {
        h0 = histw[l * 4 + 0]; h1 = histw[l * 4 + 1];
        h2 = histw[l * 4 + 2]; h3 = histw[l * 4 + 3];
      }
      unsigned lsum = h0 + h1 + h2 + h3;
      unsigned g = lsum;  // inclusive suffix scan across lanes
#pragma unroll
      for (int off = 1; off < 64; off <<= 1) {
        unsigned t = __shfl_down(g, off, 64);
        if (l + off < 64) g += t;
      }
      unsigned above = g - lsum;
      unsigned suf3 = h3 + above;
      unsigned suf2 = h2 + suf3;
      unsigned suf1 = h1 + suf2;
      unsigned suf0 = h0 + suf1;
      const unsigned kk = (unsigned)sh_k;
      const unsigned prefc = sh_pref;
      unsigned ge, geN;
      ge = suf0; geN = suf1;
      if (ge >= kk && geN < kk) { sh_pref = prefc | ((unsigned)(4 * l + 0) << shift); sh_k = (int)(kk - geN); }
      ge = suf1; geN = suf2;
      if (ge >= kk && geN < kk) { sh_pref = prefc | ((unsigned)(4 * l + 1) << shift); sh_k = (int)(kk - geN); }
      ge = suf2; geN = suf3;
      if (ge >= kk && geN < kk) { sh_pref = prefc | ((unsigned)(4 * l + 2) << shift); sh_k = (int)(kk - geN); }
      ge = suf3; geN = above;
      if (ge >= kk && geN < kk) { sh_pref = prefc | ((unsigned)(4 * l + 3) << shift); sh_k = (int)(kk - geN); }
    }
    __syncthreads();
  }
  const float thr = finv(sh_pref);

  // probs in registers + Z (wave-shuffle reduction)
  float4 pr[4];
  float lz = 0.f;
#pragma unroll
  for (int j = 0; j < 4; ++j) {
    float4 x = v[j];
    pr[j].x = (x.x >= thr) ? __expf(x.x - maxv) : 0.f;
    pr[j].y = (x.y >= thr) ? __expf(x.y - maxv) : 0.f;
    pr[j].z = (x.z >= thr) ? __expf(x.z - maxv) : 0.f;
    pr[j].w = (x.w >= thr) ? __expf(x.w - maxv) : 0.f;
    lz += pr[j].x + pr[j].y + pr[j].z + pr[j].w;
  }
#pragma unroll
  for (int off = 32; off > 0; off >>= 1) lz += __shfl_xor(lz, off);
  if (lane == 0) red4[wv] = lz;
  __syncthreads();
  if (tid == 0) sh_zinv = 1.0f / (red4[0] + red4[1] + red4[2] + red4[3]);
  __syncthreads();
  const float zinv = sh_zinv;

  // dense attn write (from registers) + kept list (index + raw prob)
  float4* arow4 = (float4*)(attn + ((size_t)b * SS + s) * MM);
#pragma unroll
  for (int j = 0; j < 4; ++j) {
    int m4 = tid + 256 * j;
    float4 p = pr[j];
    arow4[m4] = make_float4(p.x * zinv, p.y * zinv, p.z * zinv, p.w * zinv);
    int mb = m4 * 4;
    if (p.x > 0.f) { int q = atomicAdd(&sh_nkept, 1); if (q < NKEPT) { kept_m[q] = mb + 0; kept_p[q] = p.x; } }
    if (p.y > 0.f) { int q = atomicAdd(&sh_nkept, 1); if (q < NKEPT) { kept_m[q] = mb + 1; kept_p[q] = p.y; } }
    if (p.z > 0.f) { int q = atomicAdd(&sh_nkept, 1); if (q < NKEPT) { kept_m[q] = mb + 2; kept_p[q] = p.z; } }
    if (p.w > 0.f) { int q = atomicAdd(&sh_nkept, 1); if (q < NKEPT) { kept_m[q] = mb + 3; kept_p[q] = p.w; } }
  }
  __syncthreads();
  const int nk = min(sh_nkept, NKEPT);

  // retrieved[b][s][:] = sum_kept p * memory_row (float2 lanes, unrolled x4)
  float ax = 0.f, ay = 0.f;
  const float* mb_ = memory + (size_t)b * MM * DD;
  int i = 0;
  for (; i + 4 <= nk; i += 4) {
    int m0 = kept_m[i], m1 = kept_m[i + 1], m2 = kept_m[i + 2], m3 = kept_m[i + 3];
    float p0 = kept_p[i], p1 = kept_p[i + 1], p2 = kept_p[i + 2], p3 = kept_p[i + 3];
    float2 v0 = ((const float2*)(mb_ + (size_t)m0 * DD))[tid];
    float2 v1 = ((const float2*)(mb_ + (size_t)m1 * DD))[tid];
    float2 v2 = ((const float2*)(mb_ + (size_t)m2 * DD))[tid];
    float2 v3 = ((const float2*)(mb_ + (size_t)m3 * DD))[tid];
    ax += p0 * v0.x + p1 * v1.x + p2 * v2.x + p3 * v3.x;
    ay += p0 * v0.y + p1 * v1.y + p2 * v2.y + p3 * v3.y;
  }
  for (; i < nk; ++i) {
    int m = kept_m[i];
    float p = kept_p[i];
    float2 vv = ((const float2*)(mb_ + (size_t)m * DD))[tid];
    ax += p * vv.x;
    ay += p * vv.y;
  }
  float2* rrow = (float2*)(retrieved + ((size_t)b * SS + s) * DD);
  rrow[tid] = make_float2(ax * zinv, ay * zinv);
}

// ---------------------------------------------------------------------------
extern "C" void kernel_launch(void* const* d_in, const int* in_sizes, int n_in,
                              void* d_out, int out_size, void* d_ws,
                              size_t ws_size, hipStream_t stream) {
  float* memory = (float*)d_in[0];
  const float* usage = (const float*)d_in[1];
  const float* content = (const float*)d_in[2];
  const float* wstr = (const float*)d_in[3];
  const float* query = (const float*)d_in[4];
  const float* W = (const float*)d_in[5];
  const float* ttab = (const float*)d_in[6];
  const float* decay = (const float*)d_in[7];
  const int* vmask = (const int*)d_in[8];
  const int* widx = (const int*)d_in[9];
  const int* topk = (const int*)d_in[10];

  float* out = (float*)d_out;
  float* retrieved = out;                              // B*S*D floats
  float* attn = out + (size_t)BB * SS * DD;            // B*S*M floats
  float* usage_out = attn + (size_t)BB * SS * MM;      // B*M floats

  const size_t qsz = (size_t)BB * SS * DD;             // elems per q array
  float* scores = (float*)d_ws;                        // 16 MB
  f16* q1;
  f16* q2;
  size_t need = (size_t)BB * SS * MM * 4 + 2 * qsz * 2;
  if (ws_size >= need) {
    q1 = (f16*)(scores + (size_t)BB * SS * MM);
    q2 = q1 + qsz;
  } else {
    q2 = (f16*)(attn + (size_t)BB * SS * MM) - qsz;
    q1 = q2 - qsz;
  }

  prep_kernel<<<8 + 512, 256, 0, stream>>>(memory, usage, content, wstr, ttab,
                                           decay, widx, usage_out, query, W,
                                           q1, q2);
  gemm_scores_mfma<<<dim3((MM / 64) * BB), 256, 0, stream>>>(q1, q2, memory,
                                                             scores);
  select_kernel<<<dim3(SS * BB), 256, 0, stream>>>(scores, vmask, widx, topk,
                                                   memory, retrieved, attn);
}